// Round 9
// baseline (170.421 us; speedup 1.0000x reference)
//
#include <hip/hip_runtime.h>
#include <hip/hip_bf16.h>
#include <math.h>

// R9: 4 dispatches. xT eliminated (both consumers read NCHW x directly);
// sample + output GEMM fused at 4 blocks/CU (16-px blocks, 39 KB LDS).

using bf16x8 = __attribute__((ext_vector_type(8))) short;
using f32x4  = __attribute__((ext_vector_type(4))) float;

#define GLOBAL_AS __attribute__((address_space(1)))
#define LDS_AS    __attribute__((address_space(3)))

static __device__ inline void g2lds16(const void* g, void* l) {
  __builtin_amdgcn_global_load_lds((const GLOBAL_AS int*)g, (LDS_AS int*)l, 16, 0, 0);
}
static __device__ inline unsigned short f2bf(float v) {
  __hip_bfloat16 b = __float2bfloat16(v);
  return *reinterpret_cast<unsigned short*>(&b);
}
static __device__ inline float us2f(unsigned short u) {
  union { unsigned u; float f; } c; c.u = ((unsigned)u) << 16; return c.f;
}

// ---------------- weight prep: W[k][n] fp32 -> Bt[n][k] bf16 (+pad) ---------
__global__ __launch_bounds__(256) void prep_k(
    const float* __restrict__ inp_w, const float* __restrict__ off_w,
    const float* __restrict__ off_b, const float* __restrict__ mask_w,
    const float* __restrict__ mask_b, const float* __restrict__ out_w,
    __hip_bfloat16* __restrict__ BtI, __hip_bfloat16* __restrict__ BtOM,
    __hip_bfloat16* __restrict__ BtO, float* __restrict__ bOM)
{
  int b = blockIdx.x, t = threadIdx.x;   // t = k index
  if (b < 256) {
    int n = b;
    BtI[n * 256 + t] = __float2bfloat16(inp_w[t * 256 + n]);
  } else if (b < 768) {
    int n = b - 256;
    float v = 0.f;
    if (n < 288) v = off_w[t * 288 + n];
    else if (n < 432) v = mask_w[t * 144 + (n - 288)];
    BtOM[n * 256 + t] = __float2bfloat16(v);
    if (b == 256) {
      for (int idx = t; idx < 512; idx += 256) {
        float bv = (idx < 288) ? off_b[idx] : ((idx < 432) ? mask_b[idx - 288] : 0.f);
        bOM[idx] = bv;
      }
    }
  } else {
    int n = b - 768;
    BtO[n * 256 + t] = __float2bfloat16(out_w[t * 256 + n]);
  }
}

// ---------------- input-proj GEMM: A from NCHW fp32 x -----------------------
// 64x64 tile, BK=32. Asf = fp32 [k][64]; fragments converted on build.
__global__ __launch_bounds__(256) void gemm_i(
    const float* __restrict__ x, const __hip_bfloat16* __restrict__ BtI,
    const float* __restrict__ inp_b, __hip_bfloat16* __restrict__ xpu)
{
  __shared__ __align__(16) char smem[12288];
  float* Asf = (float*)smem;                 // [32][64] fp32 = 8192 B
  short* Bs  = (short*)(smem + 8192);        // [64][32] bf16 = 4096 B
  const int t = threadIdx.x;
  const int n0 = blockIdx.x * 64;
  const size_t m0 = (size_t)blockIdx.y * 64;
  const int n4 = (int)(m0 >> 12), hw0 = (int)(m0 & 4095);

  const int wave = t >> 6, lane = t & 63;
  const int quad = lane >> 4, lr = lane & 15;
  const int wm = wave >> 1, wn = wave & 1;

  f32x4 acc[2][2];
  #pragma unroll
  for (int i = 0; i < 2; ++i)
    #pragma unroll
    for (int j = 0; j < 2; ++j)
      acc[i][j] = (f32x4){0.f, 0.f, 0.f, 0.f};

  for (int kt = 0; kt < 256; kt += 32) {
    #pragma unroll
    for (int j = 0; j < 2; ++j) {          // A: 512 chunks of 16 B
      int idx = j * 256 + t;
      int kk = idx >> 4, px4 = (idx & 15) * 4;
      g2lds16(x + (size_t)n4 * 1048576 + (size_t)(kt + kk) * 4096 + hw0 + px4,
              (char*)Asf + idx * 16);
    }
    g2lds16(BtI + (size_t)(n0 + (t >> 2)) * 256 + kt + (t & 3) * 8,
            (char*)Bs + t * 16);
    __syncthreads();
    bf16x8 bfv[2];
    #pragma unroll
    for (int ni = 0; ni < 2; ++ni)
      bfv[ni] = *(const bf16x8*)&Bs[(wn * 32 + ni * 16 + lr) * 32 + quad * 8];
    #pragma unroll
    for (int mi = 0; mi < 2; ++mi) {
      int m = wm * 32 + mi * 16 + lr;
      bf16x8 af;
      #pragma unroll
      for (int j2 = 0; j2 < 8; ++j2)
        ((unsigned short*)&af)[j2] = f2bf(Asf[(quad * 8 + j2) * 64 + m]);
      #pragma unroll
      for (int ni = 0; ni < 2; ++ni)
        acc[mi][ni] = __builtin_amdgcn_mfma_f32_16x16x32_bf16(af, bfv[ni], acc[mi][ni], 0, 0, 0);
    }
    __syncthreads();
  }

  #pragma unroll
  for (int mi = 0; mi < 2; ++mi) {
    #pragma unroll
    for (int ni = 0; ni < 2; ++ni) {
      int col = n0 + wn * 32 + ni * 16 + lr;
      float bv = inp_b[col];
      #pragma unroll
      for (int reg = 0; reg < 4; ++reg) {
        size_t m = m0 + wm * 32 + mi * 16 + quad * 4 + reg;
        xpu[m * 256 + col] = __float2bfloat16(acc[mi][ni][reg] + bv);
      }
    }
  }
}

// ---------------- stage2: dwconv(from x fp32) + LN + GELU + OM GEMM ---------
// block = one image row (64 px), 1024 threads. x1 lives only in LDS.
__global__ __launch_bounds__(1024) void stage2_k(
    const float* __restrict__ x,
    const float* __restrict__ dw_w, const float* __restrict__ dw_b,
    const float* __restrict__ ln_g, const float* __restrict__ ln_b,
    const __hip_bfloat16* __restrict__ BtOM, const float* __restrict__ bOM,
    __hip_bfloat16* __restrict__ om)
{
  __shared__ __align__(16) char smem[62464];
  unsigned short* x1t = (unsigned short*)smem;                 // [64][264] 33792 B (persistent)
  unsigned short* xs  = (unsigned short*)(smem + 33792);       // [3][32][72] 13824 B
  float* wgt  = (float*)(smem + 33792 + 13824);                // [9][32] 1152 B
  float* psq  = (float*)(smem + 33792 + 13824 + 1152);         // ps|pq 8192 B
  float* murs = (float*)(smem + 33792 + 13824 + 1152 + 8192);  // mu|rs 512 B
  short* Bs   = (short*)(smem + 33792);                        // GEMM: [448][32] 28672 B

  const int blk = blockIdx.x;
  const int n4 = blk >> 6, h = blk & 63;
  const int t = threadIdx.x;
  const int w = t & 63, q = t >> 6;          // pixel w, channel-group q (0..15)

  float s1 = 0.f, s2 = 0.f;
  for (int chunk = 0; chunk < 8; ++chunk) {
    const int ch0 = chunk * 32;
    if (t < 768) {                           // stage xs[r][c][px] bf16 from x fp32
      int seg = t >> 3, part = t & 7;
      int r = seg >> 5, c = seg & 31;
      int px0 = part * 8;
      int hh = h + r - 1;
      float4 v0 = {0,0,0,0}, v1 = {0,0,0,0};
      if ((unsigned)hh < 64u) {
        const float* src = x + (size_t)n4 * 1048576 + (size_t)(ch0 + c) * 4096 + hh * 64 + px0;
        v0 = *(const float4*)src;
        v1 = *(const float4*)(src + 4);
      }
      uint4 u;
      u.x = (unsigned)f2bf(v0.x) | ((unsigned)f2bf(v0.y) << 16);
      u.y = (unsigned)f2bf(v0.z) | ((unsigned)f2bf(v0.w) << 16);
      u.z = (unsigned)f2bf(v1.x) | ((unsigned)f2bf(v1.y) << 16);
      u.w = (unsigned)f2bf(v1.z) | ((unsigned)f2bf(v1.w) << 16);
      *(uint4*)&xs[(r * 32 + c) * 72 + px0] = u;
    }
    if (t < 288) {                           // stage weights [p][lc]
      int p = t >> 5, lc = t & 31;
      wgt[p * 32 + lc] = dw_w[(ch0 + lc) * 9 + p];
    }
    __syncthreads();
    {                                        // conv: 2 channels per thread
      int lc = 2 * q;
      int c = ch0 + lc;
      float a0 = dw_b[c], a1 = dw_b[c + 1];
      #pragma unroll
      for (int p = 0; p < 9; ++p) {
        int dh = p / 3, dwd = p % 3 - 1;
        int ww = w + dwd;
        if ((unsigned)ww < 64u) {
          float wa = wgt[p * 32 + lc], wb = wgt[p * 32 + lc + 1];
          a0 = fmaf(us2f(xs[(dh * 32 + lc) * 72 + ww]), wa, a0);
          a1 = fmaf(us2f(xs[(dh * 32 + lc + 1) * 72 + ww]), wb, a1);
        }
      }
      s1 += a0 + a1;
      s2 = fmaf(a0, a0, fmaf(a1, a1, s2));
      *(unsigned*)&x1t[w * 264 + c] = (unsigned)f2bf(a0) | ((unsigned)f2bf(a1) << 16);
    }
    __syncthreads();                         // before next chunk overwrites xs
  }

  psq[q * 64 + w] = s1;
  psq[1024 + q * 64 + w] = s2;
  __syncthreads();
  if (t < 64) {
    float a = 0.f, b = 0.f;
    #pragma unroll
    for (int j = 0; j < 16; ++j) { a += psq[j * 64 + t]; b += psq[1024 + j * 64 + t]; }
    float mu = a * (1.f / 256.f);
    murs[t] = mu;
    murs[64 + t] = rsqrtf(b * (1.f / 256.f) - mu * mu + 1e-5f);
  }
  __syncthreads();
  {                                          // normalize + GELU in place
    float mu = murs[w], rs = murs[64 + w];
    #pragma unroll
    for (int chunk = 0; chunk < 8; ++chunk) {
      int c = chunk * 32 + 2 * q;
      unsigned pk = *(const unsigned*)&x1t[w * 264 + c];
      float v0 = us2f((unsigned short)(pk & 0xffff));
      float v1 = us2f((unsigned short)(pk >> 16));
      float y0 = fmaf((v0 - mu) * rs, ln_g[c], ln_b[c]);
      float y1 = fmaf((v1 - mu) * rs, ln_g[c + 1], ln_b[c + 1]);
      float g0 = 0.5f * y0 * (1.f + erff(y0 * 0.70710678f));
      float g1 = 0.5f * y1 * (1.f + erff(y1 * 0.70710678f));
      *(unsigned*)&x1t[w * 264 + c] = (unsigned)f2bf(g0) | ((unsigned)f2bf(g1) << 16);
    }
  }

  // OM GEMM: M=64 (pixels), N=448 (432 valid), K=256. 16 waves = 4m x 4n.
  const int wave = t >> 6, lane = t & 63;
  const int quad = lane >> 4, lr = lane & 15;
  const int wm = wave >> 2, wn = wave & 3;
  f32x4 acc[7];
  #pragma unroll
  for (int i = 0; i < 7; ++i) acc[i] = (f32x4){0.f, 0.f, 0.f, 0.f};

  for (int kt = 0; kt < 256; kt += 32) {
    __syncthreads();                         // murs/psq reads + prev Bs reads done
    {
      int col = t >> 2, kq = t & 3;
      g2lds16(BtOM + (size_t)col * 256 + kt + kq * 8, (char*)Bs + t * 16);
      int j = t + 1024;
      if (j < 1792) {
        col = j >> 2; kq = j & 3;
        g2lds16(BtOM + (size_t)col * 256 + kt + kq * 8, (char*)Bs + j * 16);
      }
    }
    __syncthreads();
    bf16x8 af = *(const bf16x8*)&x1t[(wm * 16 + lr) * 264 + kt + quad * 8];
    #pragma unroll
    for (int ni = 0; ni < 7; ++ni) {
      bf16x8 bf = *(const bf16x8*)&Bs[(wn * 112 + ni * 16 + lr) * 32 + quad * 8];
      acc[ni] = __builtin_amdgcn_mfma_f32_16x16x32_bf16(af, bf, acc[ni], 0, 0, 0);
    }
  }

  const size_t pix0 = (size_t)n4 * 4096 + (size_t)h * 64;
  #pragma unroll
  for (int ni = 0; ni < 7; ++ni) {
    int col = wn * 112 + ni * 16 + lr;
    if (col < 432) {
      float bv = bOM[col];
      #pragma unroll
      for (int reg = 0; reg < 4; ++reg) {
        int m = wm * 16 + quad * 4 + reg;
        om[(pix0 + m) * 448 + col] = __float2bfloat16(acc[ni][reg] + bv);
      }
    }
  }
}

// ---------------- fused: sampling + output GEMM + NCHW store ----------------
// block = 16 px, 256 thr; LDS 39168 B -> 4 blocks/CU. XCD-swizzled.
__global__ __launch_bounds__(256) void samp_o(
    const __hip_bfloat16* __restrict__ xpu, const __hip_bfloat16* __restrict__ om,
    const __hip_bfloat16* __restrict__ BtO, const float* __restrict__ out_b,
    float* __restrict__ out)
{
  __shared__ __align__(16) char smem[39168];
  unsigned short* oms   = (unsigned short*)smem;             // 16x448 = 14336 B
  unsigned short* sampS = (unsigned short*)(smem + 14336);   // 16x264 = 8448 B
  short* Bs = (short*)(smem + 22784);                        // 256x32 = 16384 B
  float* tb = (float*)smem;                                  // epi: [256][17] = 17408 B

  const int bid = blockIdx.x;                // 1024
  const int region = bid & 7;                // XCD under round-robin dispatch
  const int qb = bid >> 3;
  const int pix0 = region * 2048 + qb * 16;
  const int n4 = pix0 >> 12, hw0 = pix0 & 4095;
  const int t = threadIdx.x;

  {  // stage om tile: 16 px * 448 bf16 = 896 uint4
    const uint4* gsrc = (const uint4*)(om + (size_t)pix0 * 448);
    uint4* ldst = (uint4*)oms;
    #pragma unroll
    for (int r = 0; r < 4; ++r) {
      int i = t + r * 256;
      if (i < 896) ldst[i] = gsrc[i];
    }
  }
  __syncthreads();

  {  // sampling: thread = (pixel, group)
    const int g = t & 15;
    const int pl = t >> 4;
    const int hw = hw0 + pl;
    const int h = hw >> 6, w = hw & 63;

    float mk[9];
    const unsigned short* mp = &oms[pl * 448 + 288 + g * 9];
    float mx = -1e30f;
    #pragma unroll
    for (int p = 0; p < 9; ++p) { mk[p] = us2f(mp[p]); mx = fmaxf(mx, mk[p]); }
    float se = 0.f;
    #pragma unroll
    for (int p = 0; p < 9; ++p) { mk[p] = __expf(mk[p] - mx); se += mk[p]; }
    float inv = 1.f / se;
    #pragma unroll
    for (int p = 0; p < 9; ++p) mk[p] *= inv;

    const unsigned short* op = &oms[pl * 448 + g * 18];
    const __hip_bfloat16* xpg = xpu + (g << 4);
    float ax[16];
    #pragma unroll
    for (int i = 0; i < 16; ++i) ax[i] = 0.f;

    auto corner = [&](int iy, int ix, float wt) {
      if ((unsigned)(iy - 1) >= 64u || (unsigned)(ix - 1) >= 64u) return;
      const __hip_bfloat16* src =
          xpg + ((size_t)((n4 << 12) + (iy - 1) * 64 + (ix - 1)) << 8);
      uint4 u0 = *(const uint4*)src;
      uint4 u1 = *(const uint4*)(src + 8);
      const unsigned uu[8] = {u0.x, u0.y, u0.z, u0.w, u1.x, u1.y, u1.z, u1.w};
      #pragma unroll
      for (int i = 0; i < 8; ++i) {
        float lo = us2f((unsigned short)(uu[i] & 0xffff));
        float hi = us2f((unsigned short)(uu[i] >> 16));
        ax[2 * i + 0] = fmaf(wt, lo, ax[2 * i + 0]);
        ax[2 * i + 1] = fmaf(wt, hi, ax[2 * i + 1]);
      }
    };

    #pragma unroll
    for (int p = 0; p < 9; ++p) {
      float ox = us2f(op[2 * p]), oy = us2f(op[2 * p + 1]);
      float px = (float)(w + p / 3) + ox;
      float py = (float)(h + p % 3) + oy;
      float xf = floorf(px), yf = floorf(py);
      float wx = px - xf, wy = py - yf;
      int ix = (int)xf, iy = (int)yf;
      float m = mk[p];
      corner(iy,     ix,     (1.f - wy) * (1.f - wx) * m);
      corner(iy,     ix + 1, (1.f - wy) * wx * m);
      corner(iy + 1, ix,     wy * (1.f - wx) * m);
      corner(iy + 1, ix + 1, wy * wx * m);
    }

    unsigned short ub[16];
    #pragma unroll
    for (int i = 0; i < 16; ++i) ub[i] = f2bf(ax[i]);
    uint4 u0, u1;
    u0.x = (unsigned)ub[0] | ((unsigned)ub[1] << 16);
    u0.y = (unsigned)ub[2] | ((unsigned)ub[3] << 16);
    u0.z = (unsigned)ub[4] | ((unsigned)ub[5] << 16);
    u0.w = (unsigned)ub[6] | ((unsigned)ub[7] << 16);
    u1.x = (unsigned)ub[8] | ((unsigned)ub[9] << 16);
    u1.y = (unsigned)ub[10] | ((unsigned)ub[11] << 16);
    u1.z = (unsigned)ub[12] | ((unsigned)ub[13] << 16);
    u1.w = (unsigned)ub[14] | ((unsigned)ub[15] << 16);
    *(uint4*)&sampS[pl * 264 + g * 16] = u0;
    *(uint4*)&sampS[pl * 264 + g * 16 + 8] = u1;
  }
  __syncthreads();

  // GEMM: M=16, N=256, K=256; 4 waves = 4 n-quadrants of 64 cols.
  const int wave = t >> 6, lane = t & 63;
  const int quad = lane >> 4, lr = lane & 15;
  f32x4 acc[4];
  #pragma unroll
  for (int i = 0; i < 4; ++i) acc[i] = (f32x4){0.f, 0.f, 0.f, 0.f};

  for (int kt = 0; kt < 256; kt += 32) {
    if (kt) __syncthreads();                 // prev-iter Bs reads done
    #pragma unroll
    for (int j = 0; j < 4; ++j) {            // 1024 chunks of 16 B
      int idx = j * 256 + t;
      int col = idx >> 2, kq = idx & 3;
      g2lds16(BtO + (size_t)col * 256 + kt + kq * 8, (char*)Bs + idx * 16);
    }
    __syncthreads();
    bf16x8 af = *(const bf16x8*)&sampS[lr * 264 + kt + quad * 8];
    #pragma unroll
    for (int ni = 0; ni < 4; ++ni) {
      bf16x8 bf = *(const bf16x8*)&Bs[(wave * 64 + ni * 16 + lr) * 32 + quad * 8];
      acc[ni] = __builtin_amdgcn_mfma_f32_16x16x32_bf16(af, bf, acc[ni], 0, 0, 0);
    }
  }
  __syncthreads();                           // sampS/oms dead; tb overlays

  #pragma unroll
  for (int ni = 0; ni < 4; ++ni) {
    int col = wave * 64 + ni * 16 + lr;
    float bv = out_b[col];
    #pragma unroll
    for (int reg = 0; reg < 4; ++reg)
      tb[col * 17 + quad * 4 + reg] = acc[ni][reg] + bv;
  }
  __syncthreads();

  {  // thread t = channel; 16 px contiguous -> 4 float4 stores
    int co = t;
    float* dst = out + (size_t)(n4 * 256 + co) * 4096 + hw0;
    #pragma unroll
    for (int j = 0; j < 4; ++j) {
      float4 v;
      v.x = tb[co * 17 + j * 4 + 0];
      v.y = tb[co * 17 + j * 4 + 1];
      v.z = tb[co * 17 + j * 4 + 2];
      v.w = tb[co * 17 + j * 4 + 3];
      *(float4*)(dst + j * 4) = v;
    }
  }
}

extern "C" void kernel_launch(void* const* d_in, const int* in_sizes, int n_in,
                              void* d_out, int out_size, void* d_ws, size_t ws_size,
                              hipStream_t stream) {
  const float* x      = (const float*)d_in[0];
  const float* dw_w   = (const float*)d_in[1];
  const float* dw_b   = (const float*)d_in[2];
  const float* ln_g   = (const float*)d_in[3];
  const float* ln_b   = (const float*)d_in[4];
  const float* off_w  = (const float*)d_in[5];
  const float* off_b  = (const float*)d_in[6];
  const float* mask_w = (const float*)d_in[7];
  const float* mask_b = (const float*)d_in[8];
  const float* inp_w  = (const float*)d_in[9];
  const float* inp_b  = (const float*)d_in[10];
  const float* out_w  = (const float*)d_in[11];
  const float* out_b  = (const float*)d_in[12];
  float* out = (float*)d_out;

  char* w0 = (char*)d_ws;
  __hip_bfloat16* xpu  = (__hip_bfloat16*)(w0);               //  8,388,608 B
  __hip_bfloat16* om   = (__hip_bfloat16*)(w0 + 8388608);     // 14,680,064 B
  __hip_bfloat16* BtI  = (__hip_bfloat16*)(w0 + 23068672);    //    131,072 B
  __hip_bfloat16* BtOM = (__hip_bfloat16*)(w0 + 23199744);    //    262,144 B
  __hip_bfloat16* BtO  = (__hip_bfloat16*)(w0 + 23461888);    //    131,072 B
  float*          bOM  = (float*)(w0 + 23592960);             //      2,048 B
  if (ws_size < 23595008) return;

  prep_k<<<1024, 256, 0, stream>>>(inp_w, off_w, off_b, mask_w, mask_b, out_w,
                                   BtI, BtOM, BtO, bOM);
  gemm_i<<<dim3(4, 256), 256, 0, stream>>>(x, BtI, inp_b, xpu);
  stage2_k<<<256, 1024, 0, stream>>>(x, dw_w, dw_b, ln_g, ln_b, BtOM, bOM, om);
  samp_o<<<1024, 256, 0, stream>>>(xpu, om, BtO, out_b, out);
}

// Round 10
// 164.920 us; speedup vs baseline: 1.0334x; 1.0334x over previous
//
#include <hip/hip_runtime.h>
#include <hip/hip_bf16.h>
#include <math.h>

// R10: 3 dispatches. input-proj GEMM fused INTO stage2 (reuses conv's staged
// bf16 x tiles as MFMA A-operand). samp_o unchanged from R9.

using bf16x8 = __attribute__((ext_vector_type(8))) short;
using f32x4  = __attribute__((ext_vector_type(4))) float;

#define GLOBAL_AS __attribute__((address_space(1)))
#define LDS_AS    __attribute__((address_space(3)))

static __device__ inline void g2lds16(const void* g, void* l) {
  __builtin_amdgcn_global_load_lds((const GLOBAL_AS int*)g, (LDS_AS int*)l, 16, 0, 0);
}
static __device__ inline unsigned short f2bf(float v) {
  __hip_bfloat16 b = __float2bfloat16(v);
  return *reinterpret_cast<unsigned short*>(&b);
}
static __device__ inline float us2f(unsigned short u) {
  union { unsigned u; float f; } c; c.u = ((unsigned)u) << 16; return c.f;
}

// ---------------- weight prep: W[k][n] fp32 -> Bt[n][k] bf16 (+pad) ---------
__global__ __launch_bounds__(256) void prep_k(
    const float* __restrict__ inp_w, const float* __restrict__ off_w,
    const float* __restrict__ off_b, const float* __restrict__ mask_w,
    const float* __restrict__ mask_b, const float* __restrict__ out_w,
    __hip_bfloat16* __restrict__ BtI, __hip_bfloat16* __restrict__ BtOM,
    __hip_bfloat16* __restrict__ BtO, float* __restrict__ bOM)
{
  int b = blockIdx.x, t = threadIdx.x;   // t = k index
  if (b < 256) {
    int n = b;
    BtI[n * 256 + t] = __float2bfloat16(inp_w[t * 256 + n]);
  } else if (b < 768) {
    int n = b - 256;
    float v = 0.f;
    if (n < 288) v = off_w[t * 288 + n];
    else if (n < 432) v = mask_w[t * 144 + (n - 288)];
    BtOM[n * 256 + t] = __float2bfloat16(v);
    if (b == 256) {
      for (int idx = t; idx < 512; idx += 256) {
        float bv = (idx < 288) ? off_b[idx] : ((idx < 432) ? mask_b[idx - 288] : 0.f);
        bOM[idx] = bv;
      }
    }
  } else {
    int n = b - 768;
    BtO[n * 256 + t] = __float2bfloat16(out_w[t * 256 + n]);
  }
}

// ---------------- stage2: dwconv + LN + GELU + OM GEMM + INPUT-PROJ GEMM ----
// block = one image row (64 px), 1024 threads (16 waves).
// LDS map: [0,33792) x1t persist | [33792,64000) region2 | [64000,65152) wgt
//   region2 phases: chunks: xs(13824)+BsI(16384) -> psq(8192) -> BsOM(28672)
//   murs(512) lives in wgt area after chunk loop.
__global__ __launch_bounds__(1024) void stage2_k(
    const float* __restrict__ x,
    const float* __restrict__ dw_w, const float* __restrict__ dw_b,
    const float* __restrict__ ln_g, const float* __restrict__ ln_b,
    const __hip_bfloat16* __restrict__ BtI, const float* __restrict__ inp_b,
    const __hip_bfloat16* __restrict__ BtOM, const float* __restrict__ bOM,
    __hip_bfloat16* __restrict__ xpu, __hip_bfloat16* __restrict__ om)
{
  __shared__ __align__(16) char smem[65152];
  unsigned short* x1t = (unsigned short*)smem;                 // [64][264]
  unsigned short* xs  = (unsigned short*)(smem + 33792);       // [3][32][72]
  short* BsI  = (short*)(smem + 33792 + 13824);                // [256][32]
  float* wgt  = (float*)(smem + 64000);                        // [9][32]
  float* psq  = (float*)(smem + 33792);                        // overlay
  float* murs = (float*)(smem + 64000);                        // overlay wgt
  short* BsOM = (short*)(smem + 33792);                        // overlay GEMM

  const int blk = blockIdx.x;
  const int n4 = blk >> 6, h = blk & 63;
  const int t = threadIdx.x;
  const int w = t & 63, q = t >> 6;          // pixel w, channel-group q (0..15)

  const int wave = t >> 6, lane = t & 63;
  const int quad = lane >> 4, lr = lane & 15;
  const int wm = wave >> 2, wn = wave & 3;   // 4 m-tiles x 4 n-blocks

  f32x4 acc_i[4];                            // input-proj acc: m=wm tile, 4 ni
  #pragma unroll
  for (int i = 0; i < 4; ++i) acc_i[i] = (f32x4){0.f, 0.f, 0.f, 0.f};

  float s1 = 0.f, s2 = 0.f;
  for (int chunk = 0; chunk < 8; ++chunk) {
    const int ch0 = chunk * 32;
    if (t < 768) {                           // stage xs[r][c][px] bf16 from x fp32
      int seg = t >> 3, part = t & 7;
      int r = seg >> 5, c = seg & 31;
      int px0 = part * 8;
      int hh = h + r - 1;
      float4 v0 = {0,0,0,0}, v1 = {0,0,0,0};
      if ((unsigned)hh < 64u) {
        const float* src = x + (size_t)n4 * 1048576 + (size_t)(ch0 + c) * 4096 + hh * 64 + px0;
        v0 = *(const float4*)src;
        v1 = *(const float4*)(src + 4);
      }
      uint4 u;
      u.x = (unsigned)f2bf(v0.x) | ((unsigned)f2bf(v0.y) << 16);
      u.y = (unsigned)f2bf(v0.z) | ((unsigned)f2bf(v0.w) << 16);
      u.z = (unsigned)f2bf(v1.x) | ((unsigned)f2bf(v1.y) << 16);
      u.w = (unsigned)f2bf(v1.z) | ((unsigned)f2bf(v1.w) << 16);
      *(uint4*)&xs[(r * 32 + c) * 72 + px0] = u;
    }
    if (t < 288) {                           // stage weights [p][lc]
      int p = t >> 5, lc = t & 31;
      wgt[p * 32 + lc] = dw_w[(ch0 + lc) * 9 + p];
    }
    // stage BsI k-slab: [n=0..255][k=ch0..ch0+32) -- 1024 x 16B
    g2lds16(BtI + (size_t)(t >> 2) * 256 + ch0 + (t & 3) * 8, (char*)BsI + t * 16);
    __syncthreads();
    {                                        // conv: 2 channels per thread
      int lc = 2 * q;
      int c = ch0 + lc;
      float a0 = dw_b[c], a1 = dw_b[c + 1];
      #pragma unroll
      for (int p = 0; p < 9; ++p) {
        int dh = p / 3, dwd = p % 3 - 1;
        int ww = w + dwd;
        if ((unsigned)ww < 64u) {
          float wa = wgt[p * 32 + lc], wb = wgt[p * 32 + lc + 1];
          a0 = fmaf(us2f(xs[(dh * 32 + lc) * 72 + ww]), wa, a0);
          a1 = fmaf(us2f(xs[(dh * 32 + lc + 1) * 72 + ww]), wb, a1);
        }
      }
      s1 += a0 + a1;
      s2 = fmaf(a0, a0, fmaf(a1, a1, s2));
      *(unsigned*)&x1t[w * 264 + c] = (unsigned)f2bf(a0) | ((unsigned)f2bf(a1) << 16);
    }
    {                                        // input-proj partial: K=32 slab
      bf16x8 af;                             // A[m=px][k] from xs center row
      #pragma unroll
      for (int j = 0; j < 8; ++j)
        ((unsigned short*)&af)[j] = xs[(32 + quad * 8 + j) * 72 + wm * 16 + lr];
      #pragma unroll
      for (int ni = 0; ni < 4; ++ni) {
        bf16x8 bf = *(const bf16x8*)&BsI[(wn * 64 + ni * 16 + lr) * 32 + quad * 8];
        acc_i[ni] = __builtin_amdgcn_mfma_f32_16x16x32_bf16(af, bf, acc_i[ni], 0, 0, 0);
      }
    }
    __syncthreads();                         // before next chunk restages
  }

  // xpu epilogue (registers only; no barrier needed first)
  const size_t pix0 = (size_t)n4 * 4096 + (size_t)h * 64;
  #pragma unroll
  for (int ni = 0; ni < 4; ++ni) {
    int col = wn * 64 + ni * 16 + lr;
    float bv = inp_b[col];
    #pragma unroll
    for (int reg = 0; reg < 4; ++reg) {
      int m = wm * 16 + quad * 4 + reg;
      xpu[(pix0 + m) * 256 + col] = __float2bfloat16(acc_i[ni][reg] + bv);
    }
  }

  // LN reduce (psq overlays region2 -- all xs/BsI reads done at loop-end sync)
  psq[q * 64 + w] = s1;
  psq[1024 + q * 64 + w] = s2;
  __syncthreads();
  if (t < 64) {
    float a = 0.f, b = 0.f;
    #pragma unroll
    for (int j = 0; j < 16; ++j) { a += psq[j * 64 + t]; b += psq[1024 + j * 64 + t]; }
    float mu = a * (1.f / 256.f);
    murs[t] = mu;
    murs[64 + t] = rsqrtf(b * (1.f / 256.f) - mu * mu + 1e-5f);
  }
  __syncthreads();
  {                                          // normalize + GELU in place
    float mu = murs[w], rs = murs[64 + w];
    #pragma unroll
    for (int chunk = 0; chunk < 8; ++chunk) {
      int c = chunk * 32 + 2 * q;
      unsigned pk = *(const unsigned*)&x1t[w * 264 + c];
      float v0 = us2f((unsigned short)(pk & 0xffff));
      float v1 = us2f((unsigned short)(pk >> 16));
      float y0 = fmaf((v0 - mu) * rs, ln_g[c], ln_b[c]);
      float y1 = fmaf((v1 - mu) * rs, ln_g[c + 1], ln_b[c + 1]);
      float g0 = 0.5f * y0 * (1.f + erff(y0 * 0.70710678f));
      float g1 = 0.5f * y1 * (1.f + erff(y1 * 0.70710678f));
      *(unsigned*)&x1t[w * 264 + c] = (unsigned)f2bf(g0) | ((unsigned)f2bf(g1) << 16);
    }
  }

  // OM GEMM: M=64 (pixels), N=448 (432 valid), K=256. 16 waves = 4m x 4n.
  f32x4 acc[7];
  #pragma unroll
  for (int i = 0; i < 7; ++i) acc[i] = (f32x4){0.f, 0.f, 0.f, 0.f};

  for (int kt = 0; kt < 256; kt += 32) {
    __syncthreads();                         // x1t writes visible / prev BsOM reads done / psq dead
    {
      int col = t >> 2, kq = t & 3;
      g2lds16(BtOM + (size_t)col * 256 + kt + kq * 8, (char*)BsOM + t * 16);
      int j = t + 1024;
      if (j < 1792) {
        col = j >> 2; kq = j & 3;
        g2lds16(BtOM + (size_t)col * 256 + kt + kq * 8, (char*)BsOM + j * 16);
      }
    }
    __syncthreads();
    bf16x8 af = *(const bf16x8*)&x1t[(wm * 16 + lr) * 264 + kt + quad * 8];
    #pragma unroll
    for (int ni = 0; ni < 7; ++ni) {
      bf16x8 bf = *(const bf16x8*)&BsOM[(wn * 112 + ni * 16 + lr) * 32 + quad * 8];
      acc[ni] = __builtin_amdgcn_mfma_f32_16x16x32_bf16(af, bf, acc[ni], 0, 0, 0);
    }
  }

  #pragma unroll
  for (int ni = 0; ni < 7; ++ni) {
    int col = wn * 112 + ni * 16 + lr;
    if (col < 432) {
      float bv = bOM[col];
      #pragma unroll
      for (int reg = 0; reg < 4; ++reg) {
        int m = wm * 16 + quad * 4 + reg;
        om[(pix0 + m) * 448 + col] = __float2bfloat16(acc[ni][reg] + bv);
      }
    }
  }
}

// ---------------- fused: sampling + output GEMM + NCHW store ----------------
// block = 16 px, 256 thr; LDS 39168 B -> 4 blocks/CU. XCD-swizzled.
__global__ __launch_bounds__(256) void samp_o(
    const __hip_bfloat16* __restrict__ xpu, const __hip_bfloat16* __restrict__ om,
    const __hip_bfloat16* __restrict__ BtO, const float* __restrict__ out_b,
    float* __restrict__ out)
{
  __shared__ __align__(16) char smem[39168];
  unsigned short* oms   = (unsigned short*)smem;             // 16x448 = 14336 B
  unsigned short* sampS = (unsigned short*)(smem + 14336);   // 16x264 = 8448 B
  short* Bs = (short*)(smem + 22784);                        // 256x32 = 16384 B
  float* tb = (float*)smem;                                  // epi: [256][17] = 17408 B

  const int bid = blockIdx.x;                // 1024
  const int region = bid & 7;                // XCD under round-robin dispatch
  const int qb = bid >> 3;
  const int pix0 = region * 2048 + qb * 16;
  const int n4 = pix0 >> 12, hw0 = pix0 & 4095;
  const int t = threadIdx.x;

  {  // stage om tile: 16 px * 448 bf16 = 896 uint4
    const uint4* gsrc = (const uint4*)(om + (size_t)pix0 * 448);
    uint4* ldst = (uint4*)oms;
    #pragma unroll
    for (int r = 0; r < 4; ++r) {
      int i = t + r * 256;
      if (i < 896) ldst[i] = gsrc[i];
    }
  }
  __syncthreads();

  {  // sampling: thread = (pixel, group)
    const int g = t & 15;
    const int pl = t >> 4;
    const int hw = hw0 + pl;
    const int h = hw >> 6, w = hw & 63;

    float mk[9];
    const unsigned short* mp = &oms[pl * 448 + 288 + g * 9];
    float mx = -1e30f;
    #pragma unroll
    for (int p = 0; p < 9; ++p) { mk[p] = us2f(mp[p]); mx = fmaxf(mx, mk[p]); }
    float se = 0.f;
    #pragma unroll
    for (int p = 0; p < 9; ++p) { mk[p] = __expf(mk[p] - mx); se += mk[p]; }
    float inv = 1.f / se;
    #pragma unroll
    for (int p = 0; p < 9; ++p) mk[p] *= inv;

    const unsigned short* op = &oms[pl * 448 + g * 18];
    const __hip_bfloat16* xpg = xpu + (g << 4);
    float ax[16];
    #pragma unroll
    for (int i = 0; i < 16; ++i) ax[i] = 0.f;

    auto corner = [&](int iy, int ix, float wt) {
      if ((unsigned)(iy - 1) >= 64u || (unsigned)(ix - 1) >= 64u) return;
      const __hip_bfloat16* src =
          xpg + ((size_t)((n4 << 12) + (iy - 1) * 64 + (ix - 1)) << 8);
      uint4 u0 = *(const uint4*)src;
      uint4 u1 = *(const uint4*)(src + 8);
      const unsigned uu[8] = {u0.x, u0.y, u0.z, u0.w, u1.x, u1.y, u1.z, u1.w};
      #pragma unroll
      for (int i = 0; i < 8; ++i) {
        float lo = us2f((unsigned short)(uu[i] & 0xffff));
        float hi = us2f((unsigned short)(uu[i] >> 16));
        ax[2 * i + 0] = fmaf(wt, lo, ax[2 * i + 0]);
        ax[2 * i + 1] = fmaf(wt, hi, ax[2 * i + 1]);
      }
    };

    #pragma unroll
    for (int p = 0; p < 9; ++p) {
      float ox = us2f(op[2 * p]), oy = us2f(op[2 * p + 1]);
      float px = (float)(w + p / 3) + ox;
      float py = (float)(h + p % 3) + oy;
      float xf = floorf(px), yf = floorf(py);
      float wx = px - xf, wy = py - yf;
      int ix = (int)xf, iy = (int)yf;
      float m = mk[p];
      corner(iy,     ix,     (1.f - wy) * (1.f - wx) * m);
      corner(iy,     ix + 1, (1.f - wy) * wx * m);
      corner(iy + 1, ix,     wy * (1.f - wx) * m);
      corner(iy + 1, ix + 1, wy * wx * m);
    }

    unsigned short ub[16];
    #pragma unroll
    for (int i = 0; i < 16; ++i) ub[i] = f2bf(ax[i]);
    uint4 u0, u1;
    u0.x = (unsigned)ub[0] | ((unsigned)ub[1] << 16);
    u0.y = (unsigned)ub[2] | ((unsigned)ub[3] << 16);
    u0.z = (unsigned)ub[4] | ((unsigned)ub[5] << 16);
    u0.w = (unsigned)ub[6] | ((unsigned)ub[7] << 16);
    u1.x = (unsigned)ub[8] | ((unsigned)ub[9] << 16);
    u1.y = (unsigned)ub[10] | ((unsigned)ub[11] << 16);
    u1.z = (unsigned)ub[12] | ((unsigned)ub[13] << 16);
    u1.w = (unsigned)ub[14] | ((unsigned)ub[15] << 16);
    *(uint4*)&sampS[pl * 264 + g * 16] = u0;
    *(uint4*)&sampS[pl * 264 + g * 16 + 8] = u1;
  }
  __syncthreads();

  // GEMM: M=16, N=256, K=256; 4 waves = 4 n-quadrants of 64 cols.
  const int wave = t >> 6, lane = t & 63;
  const int quad = lane >> 4, lr = lane & 15;
  f32x4 acc[4];
  #pragma unroll
  for (int i = 0; i < 4; ++i) acc[i] = (f32x4){0.f, 0.f, 0.f, 0.f};

  for (int kt = 0; kt < 256; kt += 32) {
    if (kt) __syncthreads();                 // prev-iter Bs reads done
    #pragma unroll
    for (int j = 0; j < 4; ++j) {            // 1024 chunks of 16 B
      int idx = j * 256 + t;
      int col = idx >> 2, kq = idx & 3;
      g2lds16(BtO + (size_t)col * 256 + kt + kq * 8, (char*)Bs + idx * 16);
    }
    __syncthreads();
    bf16x8 af = *(const bf16x8*)&sampS[lr * 264 + kt + quad * 8];
    #pragma unroll
    for (int ni = 0; ni < 4; ++ni) {
      bf16x8 bf = *(const bf16x8*)&Bs[(wave * 64 + ni * 16 + lr) * 32 + quad * 8];
      acc[ni] = __builtin_amdgcn_mfma_f32_16x16x32_bf16(af, bf, acc[ni], 0, 0, 0);
    }
  }
  __syncthreads();                           // sampS/oms dead; tb overlays

  #pragma unroll
  for (int ni = 0; ni < 4; ++ni) {
    int col = wave * 64 + ni * 16 + lr;
    float bv = out_b[col];
    #pragma unroll
    for (int reg = 0; reg < 4; ++reg)
      tb[col * 17 + quad * 4 + reg] = acc[ni][reg] + bv;
  }
  __syncthreads();

  {  // thread t = channel; 16 px contiguous -> 4 float4 stores
    int co = t;
    float* dst = out + (size_t)(n4 * 256 + co) * 4096 + hw0;
    #pragma unroll
    for (int j = 0; j < 4; ++j) {
      float4 v;
      v.x = tb[co * 17 + j * 4 + 0];
      v.y = tb[co * 17 + j * 4 + 1];
      v.z = tb[co * 17 + j * 4 + 2];
      v.w = tb[co * 17 + j * 4 + 3];
      *(float4*)(dst + j * 4) = v;
    }
  }
}

extern "C" void kernel_launch(void* const* d_in, const int* in_sizes, int n_in,
                              void* d_out, int out_size, void* d_ws, size_t ws_size,
                              hipStream_t stream) {
  const float* x      = (const float*)d_in[0];
  const float* dw_w   = (const float*)d_in[1];
  const float* dw_b   = (const float*)d_in[2];
  const float* ln_g   = (const float*)d_in[3];
  const float* ln_b   = (const float*)d_in[4];
  const float* off_w  = (const float*)d_in[5];
  const float* off_b  = (const float*)d_in[6];
  const float* mask_w = (const float*)d_in[7];
  const float* mask_b = (const float*)d_in[8];
  const float* inp_w  = (const float*)d_in[9];
  const float* inp_b  = (const float*)d_in[10];
  const float* out_w  = (const float*)d_in[11];
  const float* out_b  = (const float*)d_in[12];
  float* out = (float*)d_out;

  char* w0 = (char*)d_ws;
  __hip_bfloat16* xpu  = (__hip_bfloat16*)(w0);               //  8,388,608 B
  __hip_bfloat16* om   = (__hip_bfloat16*)(w0 + 8388608);     // 14,680,064 B
  __hip_bfloat16* BtI  = (__hip_bfloat16*)(w0 + 23068672);    //    131,072 B
  __hip_bfloat16* BtOM = (__hip_bfloat16*)(w0 + 23199744);    //    262,144 B
  __hip_bfloat16* BtO  = (__hip_bfloat16*)(w0 + 23461888);    //    131,072 B
  float*          bOM  = (float*)(w0 + 23592960);             //      2,048 B
  if (ws_size < 23595008) return;

  prep_k<<<1024, 256, 0, stream>>>(inp_w, off_w, off_b, mask_w, mask_b, out_w,
                                   BtI, BtOM, BtO, bOM);
  stage2_k<<<256, 1024, 0, stream>>>(x, dw_w, dw_b, ln_g, ln_b, BtI, inp_b,
                                     BtOM, bOM, xpu, om);
  samp_o<<<1024, 256, 0, stream>>>(xpu, om, BtO, out_b, out);
}